// Round 7
// baseline (472.239 us; speedup 1.0000x reference)
//
#include <hip/hip_runtime.h>

#define N_IMG 100000
#define C_CLS 1000
#define CP    1024    // padded class count
#define DIM   512     // att_dim == img_dim
#define HPROJ 256     // H
#define CAP   512     // per-class bucket capacity

// ---------------------------------------------------------------------------
// One shared-memory union for all 256-thread kernels (max 39.2 KB -> 4 blk/CU)
// ---------------------------------------------------------------------------
union BSm {
    struct { float As[64][68]; float Wt[64][68]; float nps[64][17]; } p;  // proj1/projB
    struct { float Xi[64][68]; float Xj[64][68]; float rp[64][17]; } s;   // score
    struct { float Wt[64][68]; float Bt[64][68]; float nps[64][17]; } q;  // mmqt
    struct { float Wt[64][36]; float Vt[64][68]; } m2;                    // mm_out
    struct { int list[CAP]; float4 acc[128]; } g;                         // gather
};

// ---------------------------------------------------------------------------
// proj1: PT[h][i] = (A @ Wm)^T, full-K=512, fused nsum atomics.
// 64 blocks (4h x 16i), tile 64i x 64h, 4x4/thread, 256 threads.
// A staged ROW-major (no transpose scatter); inner loop steps k by 4.
// ---------------------------------------------------------------------------
__device__ __forceinline__ void proj1_dev(BSm& sm, int b, int t,
    const float* __restrict__ A0, const float* __restrict__ Wm,
    float* __restrict__ PT, float* __restrict__ nsum)
{
    const int h0 = (b & 3) * 64;
    const int i0 = (b >> 2) * 64;
    const int tx = t & 15, ty = t >> 4;
    float acc[4][4] = {};   // [iu][hv]
    for (int ch = 0; ch < 8; ++ch) {
        const int kb = ch * 64;
        __syncthreads();
        for (int l = t; l < 1024; l += 256) {     // A row-major (64 i x 64 k)
            const int r = l >> 4, f = l & 15;
            const int row = min(i0 + r, C_CLS - 1);
            *(float4*)&sm.p.As[r][4 * f] =
                *(const float4*)(A0 + (size_t)row * DIM + kb + 4 * f);
        }
        for (int l = t; l < 1024; l += 256) {     // W k-major (64 k x 64 h)
            const int kk = l >> 4, f = l & 15;
            *(float4*)&sm.p.Wt[kk][4 * f] =
                *(const float4*)(Wm + (size_t)(kb + kk) * HPROJ + h0 + 4 * f);
        }
        __syncthreads();
#pragma unroll 2
        for (int k4 = 0; k4 < 64; k4 += 4) {
            float4 a[4], w[4];
#pragma unroll
            for (int u = 0; u < 4; ++u) a[u] = *(const float4*)&sm.p.As[4 * ty + u][k4];
#pragma unroll
            for (int s = 0; s < 4; ++s) w[s] = *(const float4*)&sm.p.Wt[k4 + s][4 * tx];
#pragma unroll
            for (int u = 0; u < 4; ++u) {
                const float av[4] = {a[u].x, a[u].y, a[u].z, a[u].w};
#pragma unroll
                for (int s = 0; s < 4; ++s) {
                    acc[u][0] = fmaf(av[s], w[s].x, acc[u][0]);
                    acc[u][1] = fmaf(av[s], w[s].y, acc[u][1]);
                    acc[u][2] = fmaf(av[s], w[s].z, acc[u][2]);
                    acc[u][3] = fmaf(av[s], w[s].w, acc[u][3]);
                }
            }
        }
    }
    // transposed store: PT[h][i], thread's 4 i contiguous
#pragma unroll
    for (int hv = 0; hv < 4; ++hv) {
        float4 o = {acc[0][hv], acc[1][hv], acc[2][hv], acc[3][hv]};
        *(float4*)(PT + (size_t)(h0 + 4 * tx + hv) * CP + i0 + 4 * ty) = o;
    }
    // squared-norm partials (per-i over this block's 64 h)
#pragma unroll
    for (int u = 0; u < 4; ++u) {
        sm.p.nps[4 * ty + u][tx] = acc[u][0] * acc[u][0] + acc[u][1] * acc[u][1]
                                 + acc[u][2] * acc[u][2] + acc[u][3] * acc[u][3];
    }
    __syncthreads();
    if (t < 64) {
        float s = 0.f;
#pragma unroll 16
        for (int k = 0; k < 16; ++k) s += sm.p.nps[t][k];
        atomicAdd(&nsum[i0 + t], s);
    }
}

// ---------------------------------------------------------------------------
// projB: B[i][h] = A @ Wm, natural layout, no norms. Same shape as proj1.
// ---------------------------------------------------------------------------
__device__ __forceinline__ void projB_dev(BSm& sm, int b, int t,
    const float* __restrict__ A0, const float* __restrict__ Wm,
    float* __restrict__ B)
{
    const int h0 = (b & 3) * 64;
    const int i0 = (b >> 2) * 64;
    const int tx = t & 15, ty = t >> 4;
    float acc[4][4] = {};   // [iu][hv]
    for (int ch = 0; ch < 8; ++ch) {
        const int kb = ch * 64;
        __syncthreads();
        for (int l = t; l < 1024; l += 256) {
            const int r = l >> 4, f = l & 15;
            const int row = min(i0 + r, C_CLS - 1);
            *(float4*)&sm.p.As[r][4 * f] =
                *(const float4*)(A0 + (size_t)row * DIM + kb + 4 * f);
        }
        for (int l = t; l < 1024; l += 256) {
            const int kk = l >> 4, f = l & 15;
            *(float4*)&sm.p.Wt[kk][4 * f] =
                *(const float4*)(Wm + (size_t)(kb + kk) * HPROJ + h0 + 4 * f);
        }
        __syncthreads();
#pragma unroll 2
        for (int k4 = 0; k4 < 64; k4 += 4) {
            float4 a[4], w[4];
#pragma unroll
            for (int u = 0; u < 4; ++u) a[u] = *(const float4*)&sm.p.As[4 * ty + u][k4];
#pragma unroll
            for (int s = 0; s < 4; ++s) w[s] = *(const float4*)&sm.p.Wt[k4 + s][4 * tx];
#pragma unroll
            for (int u = 0; u < 4; ++u) {
                const float av[4] = {a[u].x, a[u].y, a[u].z, a[u].w};
#pragma unroll
                for (int s = 0; s < 4; ++s) {
                    acc[u][0] = fmaf(av[s], w[s].x, acc[u][0]);
                    acc[u][1] = fmaf(av[s], w[s].y, acc[u][1]);
                    acc[u][2] = fmaf(av[s], w[s].z, acc[u][2]);
                    acc[u][3] = fmaf(av[s], w[s].w, acc[u][3]);
                }
            }
        }
    }
    // natural store: B[i][h], thread's 4 h contiguous
#pragma unroll
    for (int u = 0; u < 4; ++u) {
        float4 o = {acc[u][0], acc[u][1], acc[u][2], acc[u][3]};
        *(float4*)(B + (size_t)(i0 + 4 * ty + u) * HPROJ + h0 + 4 * tx) = o;
    }
}

// ---------------------------------------------------------------------------
// gather: per-class mean of image_feats rows -> protos[c]. 256 threads.
// (round-0 proven version)
// ---------------------------------------------------------------------------
__device__ __forceinline__ void gather_dev(BSm& sm, int c, int t,
    const float* __restrict__ image_feats, const int* __restrict__ cnt,
    const int* __restrict__ perm, float* __restrict__ protos)
{
    const int n = min(cnt[c], CAP);
    for (int m = t; m < n; m += 256) sm.g.list[m] = perm[c * CAP + m];
    __syncthreads();
    const int half = t >> 7;
    const int tc   = t & 127;
    float4 a0 = {0,0,0,0}, a1 = {0,0,0,0}, a2 = {0,0,0,0}, a3 = {0,0,0,0};
    int m = half;
    for (; m + 6 < n; m += 8) {
        const float4 v0 = *(const float4*)(image_feats + (size_t)sm.g.list[m]     * DIM + 4 * tc);
        const float4 v1 = *(const float4*)(image_feats + (size_t)sm.g.list[m + 2] * DIM + 4 * tc);
        const float4 v2 = *(const float4*)(image_feats + (size_t)sm.g.list[m + 4] * DIM + 4 * tc);
        const float4 v3 = *(const float4*)(image_feats + (size_t)sm.g.list[m + 6] * DIM + 4 * tc);
        a0.x += v0.x; a0.y += v0.y; a0.z += v0.z; a0.w += v0.w;
        a1.x += v1.x; a1.y += v1.y; a1.z += v1.z; a1.w += v1.w;
        a2.x += v2.x; a2.y += v2.y; a2.z += v2.z; a2.w += v2.w;
        a3.x += v3.x; a3.y += v3.y; a3.z += v3.z; a3.w += v3.w;
    }
    for (; m < n; m += 2) {
        const float4 v0 = *(const float4*)(image_feats + (size_t)sm.g.list[m] * DIM + 4 * tc);
        a0.x += v0.x; a0.y += v0.y; a0.z += v0.z; a0.w += v0.w;
    }
    a0.x += a1.x + a2.x + a3.x; a0.y += a1.y + a2.y + a3.y;
    a0.z += a1.z + a2.z + a3.z; a0.w += a1.w + a2.w + a3.w;
    if (half) sm.g.acc[tc] = a0;
    __syncthreads();
    if (!half) {
        const float4 o = sm.g.acc[tc];
        const float inv = 1.0f / (float)n;
        float4 r;
        r.x = (a0.x + o.x) * inv; r.y = (a0.y + o.y) * inv;
        r.z = (a0.z + o.z) * inv; r.w = (a0.w + o.w) * inv;
        *(float4*)(protos + (size_t)c * DIM + 4 * tc) = r;
    }
}

// ---------------------------------------------------------------------------
// score: WT[j][i] = maskexp(dot_ij * rsqrt(nsum_i) * rsqrt(nsum_j)); fused
// row-sum atomics. 256 blocks (16j x 16i), 64x64 tile, 4i x 4j per thread.
// ---------------------------------------------------------------------------
__device__ __forceinline__ void score_dev(BSm& sm, int b, int t,
    const float* __restrict__ PT, const float* __restrict__ nsum,
    float* __restrict__ WT, float* __restrict__ rsum)
{
    const int j0 = (b & 15) * 64;
    const int i0 = (b >> 4) * 64;
    const int tx = t & 15, ty = t >> 4;
    float acc[4][4] = {};   // [iu][jv]
    for (int ch = 0; ch < 4; ++ch) {
        const int kb = ch * 64;
        __syncthreads();
        for (int l = t; l < 1024; l += 256) {
            const int kk = l >> 4, f = l & 15;
            const float* src = PT + (size_t)(kb + kk) * CP;
            *(float4*)&sm.s.Xi[kk][4 * f] = *(const float4*)(src + i0 + 4 * f);
            *(float4*)&sm.s.Xj[kk][4 * f] = *(const float4*)(src + j0 + 4 * f);
        }
        __syncthreads();
#pragma unroll 8
        for (int kk = 0; kk < 64; ++kk) {
            const float4 a = *(const float4*)&sm.s.Xi[kk][4 * ty];
            const float4 bb = *(const float4*)&sm.s.Xj[kk][4 * tx];
            const float av[4] = {a.x, a.y, a.z, a.w};
#pragma unroll
            for (int u = 0; u < 4; ++u) {
                acc[u][0] = fmaf(av[u], bb.x, acc[u][0]);
                acc[u][1] = fmaf(av[u], bb.y, acc[u][1]);
                acc[u][2] = fmaf(av[u], bb.z, acc[u][2]);
                acc[u][3] = fmaf(av[u], bb.w, acc[u][3]);
            }
        }
    }
    float rni[4];
#pragma unroll
    for (int u = 0; u < 4; ++u) rni[u] = rsqrtf(nsum[i0 + 4 * ty + u]);
    float rpart[4] = {0.f, 0.f, 0.f, 0.f};
#pragma unroll
    for (int v = 0; v < 4; ++v) {
        const int j = j0 + 4 * tx + v;
        const bool jvalid = (j < C_CLS);
        const float rnj = rsqrtf(nsum[j]);
        float4 o;
#pragma unroll
        for (int u = 0; u < 4; ++u) {
            const float d = acc[u][v] * rni[u] * rnj;
            const float w = (jvalid && d > 0.5f) ? __expf(10.f * d) : 0.f;
            ((float*)&o)[u] = w;
            rpart[u] += w;
        }
        *(float4*)(WT + (size_t)j * CP + i0 + 4 * ty) = o;
    }
#pragma unroll
    for (int u = 0; u < 4; ++u) sm.s.rp[4 * ty + u][tx] = rpart[u];
    __syncthreads();
    if (t < 64) {
        float s = 0.f;
#pragma unroll 16
        for (int k = 0; k < 16; ++k) s += sm.s.rp[t][k];
        const int i = i0 + t;
        if (i < C_CLS) atomicAdd(&rsum[i], s);
    }
}

// ---------------------------------------------------------------------------
// mmqt: QT[h][i] = (W @ B)^T, full-K=1024, fused nsum atomics.
// 64 blocks (4h x 16i), tile 64i x 64h, 4x4/thread, 16 chunks of BK=64.
// ---------------------------------------------------------------------------
__device__ __forceinline__ void mmqt_dev(BSm& sm, int b, int t,
    const float* __restrict__ WT, const float* __restrict__ B,
    float* __restrict__ QT, float* __restrict__ nsum)
{
    const int h0 = (b & 3) * 64;
    const int i0 = (b >> 2) * 64;
    const int tx = t & 15, ty = t >> 4;
    float acc[4][4] = {};   // [hu][iv]
    for (int ch = 0; ch < 16; ++ch) {
        const int kb = ch * 64;
        __syncthreads();
        for (int l = t; l < 1024; l += 256) {
            const int kk = l >> 4, f = l & 15;
            *(float4*)&sm.q.Wt[kk][4 * f] =
                *(const float4*)(WT + (size_t)(kb + kk) * CP + i0 + 4 * f);
            *(float4*)&sm.q.Bt[kk][4 * f] =
                *(const float4*)(B + (size_t)(kb + kk) * HPROJ + h0 + 4 * f);
        }
        __syncthreads();
#pragma unroll 8
        for (int kk = 0; kk < 64; ++kk) {
            const float4 w = *(const float4*)&sm.q.Wt[kk][4 * tx];   // i-dir
            const float4 bb = *(const float4*)&sm.q.Bt[kk][4 * ty];  // h-dir
            const float bv[4] = {bb.x, bb.y, bb.z, bb.w};
#pragma unroll
            for (int u = 0; u < 4; ++u) {
                acc[u][0] = fmaf(bv[u], w.x, acc[u][0]);
                acc[u][1] = fmaf(bv[u], w.y, acc[u][1]);
                acc[u][2] = fmaf(bv[u], w.z, acc[u][2]);
                acc[u][3] = fmaf(bv[u], w.w, acc[u][3]);
            }
        }
    }
#pragma unroll
    for (int hu = 0; hu < 4; ++hu) {
        float4 o = {acc[hu][0], acc[hu][1], acc[hu][2], acc[hu][3]};
        *(float4*)(QT + (size_t)(h0 + 4 * ty + hu) * CP + i0 + 4 * tx) = o;
    }
#pragma unroll
    for (int v = 0; v < 4; ++v) {
        sm.q.nps[4 * tx + v][ty] = acc[0][v] * acc[0][v] + acc[1][v] * acc[1][v]
                                 + acc[2][v] * acc[2][v] + acc[3][v] * acc[3][v];
    }
    __syncthreads();
    if (t < 64) {
        float s = 0.f;
#pragma unroll 16
        for (int k = 0; k < 16; ++k) s += sm.q.nps[t][k];
        atomicAdd(&nsum[i0 + t], s);
    }
}

// ---------------------------------------------------------------------------
// mm_out: out[i] = (W @ V)[i] / rsum[i], full-K=1024, V via vidx.
// 256 blocks (8c x 32i), tile 32i x 64c, 2i x 4c per thread.
// ---------------------------------------------------------------------------
__device__ __forceinline__ void mm_out_dev(BSm& sm, int b, int t,
    const float* __restrict__ WT, const float* __restrict__ V,
    const int* __restrict__ vidx, const float* __restrict__ rsum,
    float* __restrict__ Out)
{
    const int c0 = (b & 7) * 64;
    const int i0 = (b >> 3) * 32;
    const int tx = t & 15, ty = t >> 4;
    float acc[2][4] = {};
    for (int ch = 0; ch < 16; ++ch) {
        const int kb = ch * 64;
        __syncthreads();
        for (int l = t; l < 512; l += 256) {      // W-tile (64 k x 32 i)
            const int kk = l >> 3, f = l & 7;
            *(float4*)&sm.m2.Wt[kk][4 * f] =
                *(const float4*)(WT + (size_t)(kb + kk) * CP + i0 + 4 * f);
        }
        for (int l = t; l < 1024; l += 256) {     // V-tile (64 k x 64 c)
            const int kk = l >> 4, f = l & 15;
            const int jc = min(kb + kk, C_CLS - 1);
            const int vr = vidx[jc];
            *(float4*)&sm.m2.Vt[kk][4 * f] =
                *(const float4*)(V + (size_t)vr * DIM + c0 + 4 * f);
        }
        __syncthreads();
#pragma unroll 8
        for (int kk = 0; kk < 64; ++kk) {
            const float2 w = *(const float2*)&sm.m2.Wt[kk][2 * ty];
            const float4 v = *(const float4*)&sm.m2.Vt[kk][4 * tx];
            acc[0][0] = fmaf(w.x, v.x, acc[0][0]); acc[0][1] = fmaf(w.x, v.y, acc[0][1]);
            acc[0][2] = fmaf(w.x, v.z, acc[0][2]); acc[0][3] = fmaf(w.x, v.w, acc[0][3]);
            acc[1][0] = fmaf(w.y, v.x, acc[1][0]); acc[1][1] = fmaf(w.y, v.y, acc[1][1]);
            acc[1][2] = fmaf(w.y, v.z, acc[1][2]); acc[1][3] = fmaf(w.y, v.w, acc[1][3]);
        }
    }
#pragma unroll
    for (int u = 0; u < 2; ++u) {
        const int i = i0 + 2 * ty + u;
        if (i < C_CLS) {
            const float s = 1.0f / rsum[i];
            float4 o = {acc[u][0] * s, acc[u][1] * s, acc[u][2] * s, acc[u][3] * s};
            *(float4*)(Out + (size_t)i * DIM + c0 + 4 * tx) = o;
        }
    }
}

// ---------------------------------------------------------------------------
// Kernels
// ---------------------------------------------------------------------------
__global__ __launch_bounds__(256) void k_stage1(
    const float* __restrict__ attributes,
    const float* __restrict__ att_h, const float* __restrict__ att_g,
    float* __restrict__ PT, float* __restrict__ nsum1, float* __restrict__ B,
    const int* __restrict__ labels, int* __restrict__ cnt,
    int* __restrict__ perm)
{
    __shared__ BSm sm;
    const int b = blockIdx.x, t = threadIdx.x;
    if (b < 64) {
        proj1_dev(sm, b, t, attributes, att_h, PT, nsum1);
    } else if (b < 128) {
        projB_dev(sm, b - 64, t, attributes, att_g, B);
    } else {
        const int i = (b - 128) * 256 + t;
        if (i < N_IMG) {
            const int c = labels[i];
            const int p = atomicAdd(&cnt[c], 1);
            if (p < CAP) perm[c * CAP + p] = i;
        }
    }
}

__global__ __launch_bounds__(256) void k_score_gather(
    const float* __restrict__ PT, const float* __restrict__ nsum,
    float* __restrict__ WT, float* __restrict__ rsum,
    const float* __restrict__ image_feats, const int* __restrict__ cnt,
    const int* __restrict__ perm, float* __restrict__ protos, int cbase)
{
    __shared__ BSm sm;
    const int b = blockIdx.x, t = threadIdx.x;
    if (b < 256) score_dev(sm, b, t, PT, nsum, WT, rsum);
    else         gather_dev(sm, cbase + (b - 256), t, image_feats, cnt, perm, protos);
}

__global__ __launch_bounds__(256) void k_mmqt_gather(
    const float* __restrict__ WT, const float* __restrict__ B,
    float* __restrict__ QT, float* __restrict__ nsum,
    const float* __restrict__ image_feats, const int* __restrict__ cnt,
    const int* __restrict__ perm, float* __restrict__ protos, int cbase)
{
    __shared__ BSm sm;
    const int b = blockIdx.x, t = threadIdx.x;
    if (b < 64) mmqt_dev(sm, b, t, WT, B, QT, nsum);
    else        gather_dev(sm, cbase + (b - 64), t, image_feats, cnt, perm, protos);
}

__global__ __launch_bounds__(256) void k_mm_out(
    const float* __restrict__ WT, const float* __restrict__ V,
    const int* __restrict__ vidx, const float* __restrict__ rsum,
    float* __restrict__ Out)
{
    __shared__ BSm sm;
    mm_out_dev(sm, blockIdx.x, threadIdx.x, WT, V, vidx, rsum, Out);
}

// ---------------------------------------------------------------------------
extern "C" void kernel_launch(void* const* d_in, const int* in_sizes, int n_in,
                              void* d_out, int out_size, void* d_ws, size_t ws_size,
                              hipStream_t stream) {
    const float* image_feats = (const float*)d_in[0];  // [100000, 512]
    const float* attributes  = (const float*)d_in[1];  // [1000, 512]
    const float* att_g       = (const float*)d_in[2];  // [512, 256]
    const float* att_h       = (const float*)d_in[3];  // [512, 256]
    const int*   labels      = (const int*)d_in[4];    // [100000]
    const int*   tpl         = (const int*)d_in[5];    // [1000]
    float* out = (float*)d_out;                        // [1000, 512]

    float* ws     = (float*)d_ws;
    float* protos = ws;                       // 512000
    float* PT1    = protos + 512000;          // 262144  [256][1024]
    float* PT2    = PT1 + 262144;             // 262144  [256][1024]
    float* WT     = PT2 + 262144;             // 1048576 [1024][1024]
    float* B      = WT + 1048576;             // 262144  [1024][256]
    int*   cnt    = (int*)(B + 262144);       // 1024  (zero-block start)
    float* rsum1  = (float*)(cnt + 1024);     // 1024 (written, unused: scale
    float* rsum2  = rsum1 + 1024;             // 1024  cancels in stage-2 cosine)
    float* nsum1  = rsum2 + 1024;             // 1024
    float* nsum2  = nsum1 + 1024;             // 1024
    int*   perm   = (int*)(nsum2 + 1024);     // 512000

    hipMemsetAsync(cnt, 0, 5 * 1024 * sizeof(int), stream);

    // K1: proj1 (attr@att_h -> PT1, nsum1) ∥ projB (attr@att_g -> B) ∥ fill
    k_stage1<<<128 + 391, 256, 0, stream>>>(
        attributes, att_h, att_g, PT1, nsum1, B, labels, cnt, perm);
    // K2: score1 ∥ gather [0,334)
    k_score_gather<<<256 + 334, 256, 0, stream>>>(
        PT1, nsum1, WT, rsum1, image_feats, cnt, perm, protos, 0);
    // K3: mmqt (W1@B -> PT2 transposed, nsum2) ∥ gather [334,667)
    k_mmqt_gather<<<64 + 333, 256, 0, stream>>>(
        WT, B, PT2, nsum2, image_feats, cnt, perm, protos, 334);
    // K4: score2 ∥ gather [667,1000)
    k_score_gather<<<256 + 333, 256, 0, stream>>>(
        PT2, nsum2, WT, rsum2, image_feats, cnt, perm, protos, 667);
    // K5: mm_out full-K, fused 1/rsum2 scale, writes out directly
    k_mm_out<<<256, 256, 0, stream>>>(WT, protos, tpl, rsum2, out);
}

// Round 9
// 430.986 us; speedup vs baseline: 1.0957x; 1.0957x over previous
//
#include <hip/hip_runtime.h>

#define N_IMG 100000
#define C_CLS 1000
#define CP    1024    // padded class count
#define DIM   512     // att_dim == img_dim
#define HPROJ 256     // H
#define CAP   512     // per-class bucket capacity

// ---------------------------------------------------------------------------
// One shared-memory union for all 512-thread kernels (max = score: 38.3 KB)
// ---------------------------------------------------------------------------
union BSm {
    struct { float At[64][33]; float Wt[64][36]; float nps[32][17]; } p;  // proj
    struct { float Xi[64][68]; float Xj[64][68]; float rp[64][17]; } s;   // score
    struct { float Wt[64][68]; float Vt[64][68]; } m;                     // mm1
    struct { float Wt[64][36]; float Vt[64][68]; } m2;                    // mm_out
    struct { int list[CAP]; float4 acc[3][128]; } g;                      // gather
};

// ---------------------------------------------------------------------------
// proj: PT[j][i] = (A_eff @ Wm)^T, FULL-K (512), fused squared-norm partials
// atomicAdd'ed into nsum[i]. 256 blocks (8j x 32i), tile 32i x 32j, 512 thr.
// A_eff = A0  or  (Q0+Q1)/rsum (fused combine of previous stage).
// (R4-verbatim)
// ---------------------------------------------------------------------------
__device__ __forceinline__ void proj_dev(BSm& sm, int b, int t,
    const float* __restrict__ A0, const float* __restrict__ Qp,
    const float* __restrict__ rsum, const float* __restrict__ Wm,
    float* __restrict__ PT, float* __restrict__ nsum)
{
    const int j0 = (b & 7) * 32;
    const int i0 = (b >> 3) * 32;
    const int ti = t & 31;      // i lane
    const int tj = t >> 5;      // j-pair 0..15
    float acc0 = 0.f, acc1 = 0.f;
    for (int ch = 0; ch < 8; ++ch) {
        const int kb = ch * 64;
        __syncthreads();
        {   // A-tile (32 i x 64 k) k-major: one float4 per thread
            const int r = t >> 4, f = t & 15;
            const int row = min(i0 + r, C_CLS - 1);
            float4 v;
            if (A0) {
                v = *(const float4*)(A0 + (size_t)row * DIM + kb + 4 * f);
            } else {
                const float4 q0 = *(const float4*)(Qp + (size_t)row * DIM + kb + 4 * f);
                const float4 q1 = *(const float4*)(Qp + (size_t)CP * DIM + (size_t)row * DIM + kb + 4 * f);
                const float rs = 1.0f / rsum[row];
                v.x = (q0.x + q1.x) * rs; v.y = (q0.y + q1.y) * rs;
                v.z = (q0.z + q1.z) * rs; v.w = (q0.w + q1.w) * rs;
            }
            sm.p.At[4*f+0][r] = v.x; sm.p.At[4*f+1][r] = v.y;
            sm.p.At[4*f+2][r] = v.z; sm.p.At[4*f+3][r] = v.w;
        }
        {   // W-tile (64 k x 32 j): one float4 per thread
            const int kk = t >> 3, f = t & 7;
            *(float4*)&sm.p.Wt[kk][4*f] =
                *(const float4*)(Wm + (size_t)(kb + kk) * HPROJ + j0 + 4 * f);
        }
        __syncthreads();
#pragma unroll 8
        for (int kk = 0; kk < 64; ++kk) {
            const float  a = sm.p.At[kk][ti];
            const float2 w = *(const float2*)&sm.p.Wt[kk][2 * tj];
            acc0 = fmaf(a, w.x, acc0);
            acc1 = fmaf(a, w.y, acc1);
        }
    }
    const int i = i0 + ti, j = j0 + 2 * tj;
    PT[(size_t)j       * CP + i] = acc0;
    PT[(size_t)(j + 1) * CP + i] = acc1;
    sm.p.nps[ti][tj] = acc0 * acc0 + acc1 * acc1;
    __syncthreads();
    if (t < 32) {
        float s = 0.f;
#pragma unroll
        for (int k = 0; k < 16; ++k) s += sm.p.nps[t][k];
        atomicAdd(&nsum[i0 + t], s);
    }
}

// ---------------------------------------------------------------------------
// gather (2 blocks per class): block `half` sums its contiguous half of the
// class row list, scales by 1/n, atomicAdds into protos (pre-zeroed).
// Halved serial chain per block -> doubled latency-hiding parallelism.
// ---------------------------------------------------------------------------
__device__ __forceinline__ void gather_dev(BSm& sm, int c, int half, int t,
    const float* __restrict__ image_feats, const int* __restrict__ cnt,
    const int* __restrict__ perm, float* __restrict__ protos)
{
    const int n    = min(cnt[c], CAP);
    const int nh   = n >> 1;
    const int base = half ? nh : 0;
    const int cnth = half ? (n - nh) : nh;
    for (int m = t; m < cnth; m += 512) sm.g.list[m] = perm[c * CAP + base + m];
    __syncthreads();
    const int q  = t >> 7;     // row-stream quarter 0..3
    const int tc = t & 127;    // float4 column group
    float4 a0 = {0,0,0,0}, a1 = {0,0,0,0};
    int m = q;
    for (; m + 4 < cnth; m += 8) {
        const float4 v0 = *(const float4*)(image_feats + (size_t)sm.g.list[m]     * DIM + 4 * tc);
        const float4 v1 = *(const float4*)(image_feats + (size_t)sm.g.list[m + 4] * DIM + 4 * tc);
        a0.x += v0.x; a0.y += v0.y; a0.z += v0.z; a0.w += v0.w;
        a1.x += v1.x; a1.y += v1.y; a1.z += v1.z; a1.w += v1.w;
    }
    for (; m < cnth; m += 4) {
        const float4 v0 = *(const float4*)(image_feats + (size_t)sm.g.list[m] * DIM + 4 * tc);
        a0.x += v0.x; a0.y += v0.y; a0.z += v0.z; a0.w += v0.w;
    }
    a0.x += a1.x; a0.y += a1.y; a0.z += a1.z; a0.w += a1.w;
    if (q) sm.g.acc[q - 1][tc] = a0;
    __syncthreads();
    if (q == 0) {
        const float4 o1 = sm.g.acc[0][tc];
        const float4 o2 = sm.g.acc[1][tc];
        const float4 o3 = sm.g.acc[2][tc];
        const float s = 1.0f / (float)n;
        float* dst = protos + (size_t)c * DIM + 4 * tc;
        atomicAdd(dst + 0, (a0.x + o1.x + o2.x + o3.x) * s);
        atomicAdd(dst + 1, (a0.y + o1.y + o2.y + o3.y) * s);
        atomicAdd(dst + 2, (a0.z + o1.z + o2.z + o3.z) * s);
        atomicAdd(dst + 3, (a0.w + o1.w + o2.w + o3.w) * s);
    }
}

// ---------------------------------------------------------------------------
// score: WT[j][i] = maskexp(dot_ij * rsqrt(nsum_i) * rsqrt(nsum_j)); fused
// row-sum atomics. 256 blocks (16j x 16i), 64x64 tile, 2i x 4j per thread.
// (R4-verbatim)
// ---------------------------------------------------------------------------
__device__ __forceinline__ void score_dev(BSm& sm, int b, int t,
    const float* __restrict__ PT, const float* __restrict__ nsum,
    float* __restrict__ WT, float* __restrict__ rsum)
{
    const int j0 = (b & 15) * 64;
    const int i0 = (b >> 4) * 64;
    const int tx = t & 15, ty = t >> 4;   // ty 0..31
    float acc[2][4] = {};
    for (int ch = 0; ch < 4; ++ch) {
        const int kb = ch * 64;
        __syncthreads();
        for (int l = t; l < 1024; l += 512) {
            const int kk = l >> 4, f = l & 15;
            const float* src = PT + (size_t)(kb + kk) * CP;
            *(float4*)&sm.s.Xi[kk][4 * f] = *(const float4*)(src + i0 + 4 * f);
            *(float4*)&sm.s.Xj[kk][4 * f] = *(const float4*)(src + j0 + 4 * f);
        }
        __syncthreads();
#pragma unroll 8
        for (int kk = 0; kk < 64; ++kk) {
            const float2 a  = *(const float2*)&sm.s.Xi[kk][2 * ty];
            const float4 bb = *(const float4*)&sm.s.Xj[kk][4 * tx];
            const float av[2] = {a.x, a.y};
            const float bv[4] = {bb.x, bb.y, bb.z, bb.w};
#pragma unroll
            for (int u = 0; u < 2; ++u)
#pragma unroll
                for (int v = 0; v < 4; ++v)
                    acc[u][v] = fmaf(av[u], bv[v], acc[u][v]);
        }
    }
    const float rni0 = rsqrtf(nsum[i0 + 2 * ty + 0]);
    const float rni1 = rsqrtf(nsum[i0 + 2 * ty + 1]);
    float rp0 = 0.f, rp1 = 0.f;
#pragma unroll
    for (int v = 0; v < 4; ++v) {
        const int j = j0 + 4 * tx + v;
        const bool jv = (j < C_CLS);
        const float rnj = rsqrtf(nsum[j]);
        const float d0 = acc[0][v] * rni0 * rnj;
        const float d1 = acc[1][v] * rni1 * rnj;
        const float w0 = (jv && d0 > 0.5f) ? __expf(10.f * d0) : 0.f;
        const float w1 = (jv && d1 > 0.5f) ? __expf(10.f * d1) : 0.f;
        rp0 += w0; rp1 += w1;
        *(float2*)(WT + (size_t)j * CP + i0 + 2 * ty) = make_float2(w0, w1);
    }
    sm.s.rp[2 * ty + 0][tx] = rp0;
    sm.s.rp[2 * ty + 1][tx] = rp1;
    __syncthreads();
    if (t < 64) {
        float s = 0.f;
#pragma unroll 16
        for (int k = 0; k < 16; ++k) s += sm.s.rp[t][k];
        const int i = i0 + t;
        if (i < C_CLS) atomicAdd(&rsum[i], s);
    }
}

// ---------------------------------------------------------------------------
// mm1 (split-K x2): Q[kz] = W @ V partial GEMM from WT. 256 blocks (8c x 16i
// x 2kz), 64x64 tile, 2i x 4c per thread. (R4-verbatim)
// ---------------------------------------------------------------------------
__device__ __forceinline__ void mm_dev(BSm& sm, int b, int t,
    const float* __restrict__ WT, const float* __restrict__ V,
    float* __restrict__ Q)
{
    const int c0 = (b & 7) * 64;
    const int i0 = ((b >> 3) & 15) * 64;
    const int kz = b >> 7;
    const int tx = t & 15, ty = t >> 4;
    float acc[2][4] = {};
    for (int ch = 0; ch < 8; ++ch) {
        const int kb = kz * 512 + ch * 64;
        __syncthreads();
        for (int l = t; l < 1024; l += 512) {
            const int kk = l >> 4, f = l & 15;
            *(float4*)&sm.m.Wt[kk][4 * f] =
                *(const float4*)(WT + (size_t)(kb + kk) * CP + i0 + 4 * f);
            const int jc = min(kb + kk, C_CLS - 1);
            *(float4*)&sm.m.Vt[kk][4 * f] =
                *(const float4*)(V + (size_t)jc * DIM + c0 + 4 * f);
        }
        __syncthreads();
#pragma unroll 8
        for (int kk = 0; kk < 64; ++kk) {
            const float2 w = *(const float2*)&sm.m.Wt[kk][2 * ty];
            const float4 v = *(const float4*)&sm.m.Vt[kk][4 * tx];
            const float wv[2] = {w.x, w.y};
            const float vv[4] = {v.x, v.y, v.z, v.w};
#pragma unroll
            for (int u = 0; u < 2; ++u)
#pragma unroll
                for (int cv = 0; cv < 4; ++cv)
                    acc[u][cv] = fmaf(wv[u], vv[cv], acc[u][cv]);
        }
    }
    float* dst = Q + (size_t)kz * CP * DIM;
#pragma unroll
    for (int u = 0; u < 2; ++u) {
        const int i = i0 + 2 * ty + u;
        float4 o = {acc[u][0], acc[u][1], acc[u][2], acc[u][3]};
        *(float4*)(dst + (size_t)i * DIM + c0 + 4 * tx) = o;
    }
}

// ---------------------------------------------------------------------------
// mm_out (full-K, 256 blocks): out[i] = (W @ V)[i] / rsum[i], V via vidx.
// grid (8c x 32i), tile 32i x 64c, K=1024 in 16 chunks, 1i x 4c per thread.
// (R4-verbatim)
// ---------------------------------------------------------------------------
__device__ __forceinline__ void mm_out_dev(BSm& sm, int b, int t,
    const float* __restrict__ WT, const float* __restrict__ V,
    const int* __restrict__ vidx, const float* __restrict__ rsum,
    float* __restrict__ Out)
{
    const int c0 = (b & 7) * 64;
    const int i0 = (b >> 3) * 32;
    const int tx = t & 15, ty = t >> 4;   // ty 0..31 = i
    float acc[4] = {};
    for (int ch = 0; ch < 16; ++ch) {
        const int kb = ch * 64;
        __syncthreads();
        {
            const int kk = t >> 3, f = t & 7;
            *(float4*)&sm.m2.Wt[kk][4 * f] =
                *(const float4*)(WT + (size_t)(kb + kk) * CP + i0 + 4 * f);
        }
        for (int l = t; l < 1024; l += 512) {
            const int kk = l >> 4, f = l & 15;
            const int jc = min(kb + kk, C_CLS - 1);
            const int vr = vidx[jc];
            *(float4*)&sm.m2.Vt[kk][4 * f] =
                *(const float4*)(V + (size_t)vr * DIM + c0 + 4 * f);
        }
        __syncthreads();
#pragma unroll 8
        for (int kk = 0; kk < 64; ++kk) {
            const float  w = sm.m2.Wt[kk][ty];
            const float4 v = *(const float4*)&sm.m2.Vt[kk][4 * tx];
            acc[0] = fmaf(w, v.x, acc[0]);
            acc[1] = fmaf(w, v.y, acc[1]);
            acc[2] = fmaf(w, v.z, acc[2]);
            acc[3] = fmaf(w, v.w, acc[3]);
        }
    }
    const int i = i0 + ty;
    if (i < C_CLS) {
        const float s = 1.0f / rsum[i];
        float4 o = {acc[0] * s, acc[1] * s, acc[2] * s, acc[3] * s};
        *(float4*)(Out + (size_t)i * DIM + c0 + 4 * tx) = o;
    }
}

// ---------------------------------------------------------------------------
// Kernels. Gather slice mapping: gb = b - 256; class = cbase + (gb>>1),
// half = gb & 1. 400 gather blocks per slice (200 classes).
// ---------------------------------------------------------------------------
__global__ __launch_bounds__(512) void k_fill(
    const int* __restrict__ labels, int* __restrict__ cnt,
    int* __restrict__ perm)
{
    const int i = blockIdx.x * 512 + threadIdx.x;
    if (i < N_IMG) {
        const int c = labels[i];
        const int p = atomicAdd(&cnt[c], 1);
        if (p < CAP) perm[c * CAP + p] = i;
    }
}

__global__ __launch_bounds__(512) void k_projA_gather(
    const float* __restrict__ A0, const float* __restrict__ Wm,
    float* __restrict__ PT, float* __restrict__ nsum,
    const float* __restrict__ image_feats, const int* __restrict__ cnt,
    const int* __restrict__ perm, float* __restrict__ protos, int cbase)
{
    __shared__ BSm sm;
    const int b = blockIdx.x, t = threadIdx.x;
    if (b < 256) proj_dev(sm, b, t, A0, nullptr, nullptr, Wm, PT, nsum);
    else {
        const int gb = b - 256;
        gather_dev(sm, cbase + (gb >> 1), gb & 1, t, image_feats, cnt, perm, protos);
    }
}

__global__ __launch_bounds__(512) void k_projQ_gather(
    const float* __restrict__ Qp, const float* __restrict__ rsum_in,
    const float* __restrict__ Wm, float* __restrict__ PT,
    float* __restrict__ nsum,
    const float* __restrict__ image_feats, const int* __restrict__ cnt,
    const int* __restrict__ perm, float* __restrict__ protos, int cbase)
{
    __shared__ BSm sm;
    const int b = blockIdx.x, t = threadIdx.x;
    if (b < 256) proj_dev(sm, b, t, nullptr, Qp, rsum_in, Wm, PT, nsum);
    else {
        const int gb = b - 256;
        gather_dev(sm, cbase + (gb >> 1), gb & 1, t, image_feats, cnt, perm, protos);
    }
}

__global__ __launch_bounds__(512) void k_score_gather(
    const float* __restrict__ PT, const float* __restrict__ nsum,
    float* __restrict__ WT, float* __restrict__ rsum,
    const float* __restrict__ image_feats, const int* __restrict__ cnt,
    const int* __restrict__ perm, float* __restrict__ protos, int cbase)
{
    __shared__ BSm sm;
    const int b = blockIdx.x, t = threadIdx.x;
    if (b < 256) score_dev(sm, b, t, PT, nsum, WT, rsum);
    else {
        const int gb = b - 256;
        gather_dev(sm, cbase + (gb >> 1), gb & 1, t, image_feats, cnt, perm, protos);
    }
}

__global__ __launch_bounds__(512) void k_mm_gather(
    const float* __restrict__ WT, const float* __restrict__ V,
    float* __restrict__ Q,
    const float* __restrict__ image_feats, const int* __restrict__ cnt,
    const int* __restrict__ perm, float* __restrict__ protos, int cbase)
{
    __shared__ BSm sm;
    const int b = blockIdx.x, t = threadIdx.x;
    if (b < 256) mm_dev(sm, b, t, WT, V, Q);
    else {
        const int gb = b - 256;
        gather_dev(sm, cbase + (gb >> 1), gb & 1, t, image_feats, cnt, perm, protos);
    }
}

__global__ __launch_bounds__(512) void k_mm_out(
    const float* __restrict__ WT, const float* __restrict__ V,
    const int* __restrict__ vidx, const float* __restrict__ rsum,
    float* __restrict__ Out)
{
    __shared__ BSm sm;
    mm_out_dev(sm, blockIdx.x, threadIdx.x, WT, V, vidx, rsum, Out);
}

// ---------------------------------------------------------------------------
extern "C" void kernel_launch(void* const* d_in, const int* in_sizes, int n_in,
                              void* d_out, int out_size, void* d_ws, size_t ws_size,
                              hipStream_t stream) {
    const float* image_feats = (const float*)d_in[0];  // [100000, 512]
    const float* attributes  = (const float*)d_in[1];  // [1000, 512]
    const float* att_g       = (const float*)d_in[2];  // [512, 256]
    const float* att_h       = (const float*)d_in[3];  // [512, 256]
    const int*   labels      = (const int*)d_in[4];    // [100000]
    const int*   tpl         = (const int*)d_in[5];    // [1000]
    float* out = (float*)d_out;                        // [1000, 512]

    float* ws     = (float*)d_ws;
    float* protos = ws;                       // 512000 (zeroed; gather atomics)
    float* PT     = protos + 512000;          // 262144  [256][1024] (reused)
    float* WT     = PT + 262144;              // 1048576 [1024][1024]
    float* Qpart  = WT + 1048576;             // 1048576 [2][1024][512]
    int*   cnt    = (int*)(Qpart + 1048576);  // 1024  (zero-block start)
    float* rsum1  = (float*)(cnt + 1024);     // 1024
    float* rsum2  = rsum1 + 1024;             // 1024
    float* nsum1  = rsum2 + 1024;             // 1024
    float* nsum2  = nsum1 + 1024;             // 1024
    int*   perm   = (int*)(nsum2 + 1024);     // 512000

    hipMemsetAsync(cnt, 0, 5 * 1024 * sizeof(int), stream);
    hipMemsetAsync(protos, 0, 512000 * sizeof(float), stream);

    // K0: fill (own kernel so K1 can carry a gather slice)
    k_fill<<<196, 512, 0, stream>>>(labels, cnt, perm);
    // K1: proj1 (attr@att_h -> PT, nsum1) ∥ gather classes [0,200)
    k_projA_gather<<<256 + 400, 512, 0, stream>>>(
        attributes, att_h, PT, nsum1, image_feats, cnt, perm, protos, 0);
    // K2: score1 ∥ gather [200,400)
    k_score_gather<<<256 + 400, 512, 0, stream>>>(
        PT, nsum1, WT, rsum1, image_feats, cnt, perm, protos, 200);
    // K3: mm1 (split-K) ∥ gather [400,600)
    k_mm_gather<<<256 + 400, 512, 0, stream>>>(
        WT, attributes, Qpart, image_feats, cnt, perm, protos, 400);
    // K4: proj2 (combine(Qpart)/rsum1 @ att_g -> PT, nsum2) ∥ gather [600,800)
    k_projQ_gather<<<256 + 400, 512, 0, stream>>>(
        Qpart, rsum1, att_g, PT, nsum2, image_feats, cnt, perm, protos, 600);
    // K5: score2 ∥ gather [800,1000)
    k_score_gather<<<256 + 400, 512, 0, stream>>>(
        PT, nsum2, WT, rsum2, image_feats, cnt, perm, protos, 800);
    // K6: mm_out full-K, fused 1/rsum2 scale, writes out directly
    k_mm_out<<<256, 512, 0, stream>>>(WT, protos, tpl, rsum2, out);
}

// Round 10
// 410.092 us; speedup vs baseline: 1.1515x; 1.0509x over previous
//
#include <hip/hip_runtime.h>

#define N_IMG 100000
#define C_CLS 1000
#define CP    1024    // padded class count
#define DIM   512     // att_dim == img_dim
#define HPROJ 256     // H
#define CAP   512     // per-class bucket capacity

// ---------------------------------------------------------------------------
// One shared-memory union for all 512-thread kernels (max = score: 38.3 KB)
// ---------------------------------------------------------------------------
union BSm {
    struct { float At[64][33]; float Wt[64][36]; float nps[32][17]; } p;  // proj
    struct { float Xi[64][68]; float Xj[64][68]; float rp[64][17]; } s;   // score
    struct { float Wt[64][68]; float Vt[64][68]; } m;                     // mm1
    struct { float Wt[64][36]; float Vt[64][68]; } m2;                    // mm_out
    struct { int list[CAP]; float4 acc[3][128]; } g;                      // gather
};

// ---------------------------------------------------------------------------
// proj: PT[j][i] = (A_eff @ Wm)^T, FULL-K (512), fused squared-norm partials
// atomicAdd'ed into nsum[i]. 256 blocks (8j x 32i), tile 32i x 32j, 512 thr.
// A_eff = A0  or  (Q0+Q1)/rsum (fused combine of previous stage).
// ---------------------------------------------------------------------------
__device__ __forceinline__ void proj_dev(BSm& sm, int b, int t,
    const float* __restrict__ A0, const float* __restrict__ Qp,
    const float* __restrict__ rsum, const float* __restrict__ Wm,
    float* __restrict__ PT, float* __restrict__ nsum)
{
    const int j0 = (b & 7) * 32;
    const int i0 = (b >> 3) * 32;
    const int ti = t & 31;      // i lane
    const int tj = t >> 5;      // j-pair 0..15
    float acc0 = 0.f, acc1 = 0.f;
    for (int ch = 0; ch < 8; ++ch) {
        const int kb = ch * 64;
        __syncthreads();
        // stage A-tile (32 i x 64 k) k-major: one float4 per thread
        {
            const int r = t >> 4, f = t & 15;
            const int row = min(i0 + r, C_CLS - 1);
            float4 v;
            if (A0) {
                v = *(const float4*)(A0 + (size_t)row * DIM + kb + 4 * f);
            } else {
                const float4 q0 = *(const float4*)(Qp + (size_t)row * DIM + kb + 4 * f);
                const float4 q1 = *(const float4*)(Qp + (size_t)CP * DIM + (size_t)row * DIM + kb + 4 * f);
                const float rs = 1.0f / rsum[row];
                v.x = (q0.x + q1.x) * rs; v.y = (q0.y + q1.y) * rs;
                v.z = (q0.z + q1.z) * rs; v.w = (q0.w + q1.w) * rs;
            }
            sm.p.At[4*f+0][r] = v.x; sm.p.At[4*f+1][r] = v.y;
            sm.p.At[4*f+2][r] = v.z; sm.p.At[4*f+3][r] = v.w;
        }
        // stage W-tile (64 k x 32 j): one float4 per thread
        {
            const int kk = t >> 3, f = t & 7;
            *(float4*)&sm.p.Wt[kk][4*f] =
                *(const float4*)(Wm + (size_t)(kb + kk) * HPROJ + j0 + 4 * f);
        }
        __syncthreads();
#pragma unroll 8
        for (int kk = 0; kk < 64; ++kk) {
            const float  a = sm.p.At[kk][ti];
            const float2 w = *(const float2*)&sm.p.Wt[kk][2 * tj];
            acc0 = fmaf(a, w.x, acc0);
            acc1 = fmaf(a, w.y, acc1);
        }
    }
    // transposed store: PT[j][i], lanes contiguous in i
    const int i = i0 + ti, j = j0 + 2 * tj;
    PT[(size_t)j       * CP + i] = acc0;
    PT[(size_t)(j + 1) * CP + i] = acc1;
    // squared-norm partials over this block's 32 j-dims
    sm.p.nps[ti][tj] = acc0 * acc0 + acc1 * acc1;
    __syncthreads();
    if (t < 32) {
        float s = 0.f;
#pragma unroll
        for (int q = 0; q < 16; ++q) s += sm.p.nps[t][q];
        atomicAdd(&nsum[i0 + t], s);
    }
}

// ---------------------------------------------------------------------------
// gather: per-class mean of image_feats rows -> protos[c]. 512 threads.
// ---------------------------------------------------------------------------
__device__ __forceinline__ void gather_dev(BSm& sm, int c, int t,
    const float* __restrict__ image_feats, const int* __restrict__ cnt,
    const int* __restrict__ perm, float* __restrict__ protos)
{
    const int n = min(cnt[c], CAP);
    for (int m = t; m < n; m += 512) sm.g.list[m] = perm[c * CAP + m];
    __syncthreads();
    const int q  = t >> 7;     // row-stream quarter 0..3
    const int tc = t & 127;    // float4 column group
    float4 a0 = {0,0,0,0}, a1 = {0,0,0,0};
    int m = q;
    for (; m + 4 < n; m += 8) {
        const float4 v0 = *(const float4*)(image_feats + (size_t)sm.g.list[m]     * DIM + 4 * tc);
        const float4 v1 = *(const float4*)(image_feats + (size_t)sm.g.list[m + 4] * DIM + 4 * tc);
        a0.x += v0.x; a0.y += v0.y; a0.z += v0.z; a0.w += v0.w;
        a1.x += v1.x; a1.y += v1.y; a1.z += v1.z; a1.w += v1.w;
    }
    for (; m < n; m += 4) {
        const float4 v0 = *(const float4*)(image_feats + (size_t)sm.g.list[m] * DIM + 4 * tc);
        a0.x += v0.x; a0.y += v0.y; a0.z += v0.z; a0.w += v0.w;
    }
    a0.x += a1.x; a0.y += a1.y; a0.z += a1.z; a0.w += a1.w;
    if (q) sm.g.acc[q - 1][tc] = a0;
    __syncthreads();
    if (q == 0) {
        const float4 o1 = sm.g.acc[0][tc];
        const float4 o2 = sm.g.acc[1][tc];
        const float4 o3 = sm.g.acc[2][tc];
        const float inv = 1.0f / (float)n;
        float4 r;
        r.x = (a0.x + o1.x + o2.x + o3.x) * inv;
        r.y = (a0.y + o1.y + o2.y + o3.y) * inv;
        r.z = (a0.z + o1.z + o2.z + o3.z) * inv;
        r.w = (a0.w + o1.w + o2.w + o3.w) * inv;
        *(float4*)(protos + (size_t)c * DIM + 4 * tc) = r;
    }
}

// ---------------------------------------------------------------------------
// score: WT[j][i] = maskexp(dot_ij * rsqrt(nsum_i) * rsqrt(nsum_j)); fused
// row-sum atomics. Reads single PT panel.
// 256 blocks (16j x 16i), 64x64 tile, 2i x 4j per thread, 512 threads.
// ---------------------------------------------------------------------------
__device__ __forceinline__ void score_dev(BSm& sm, int b, int t,
    const float* __restrict__ PT, const float* __restrict__ nsum,
    float* __restrict__ WT, float* __restrict__ rsum)
{
    const int j0 = (b & 15) * 64;
    const int i0 = (b >> 4) * 64;
    const int tx = t & 15, ty = t >> 4;   // ty 0..31
    float acc[2][4] = {};
    for (int ch = 0; ch < 4; ++ch) {
        const int kb = ch * 64;
        __syncthreads();
        for (int l = t; l < 1024; l += 512) {
            const int kk = l >> 4, f = l & 15;
            const float* src = PT + (size_t)(kb + kk) * CP;
            *(float4*)&sm.s.Xi[kk][4 * f] = *(const float4*)(src + i0 + 4 * f);
            *(float4*)&sm.s.Xj[kk][4 * f] = *(const float4*)(src + j0 + 4 * f);
        }
        __syncthreads();
#pragma unroll 8
        for (int kk = 0; kk < 64; ++kk) {
            const float2 a  = *(const float2*)&sm.s.Xi[kk][2 * ty];
            const float4 bb = *(const float4*)&sm.s.Xj[kk][4 * tx];
            const float av[2] = {a.x, a.y};
            const float bv[4] = {bb.x, bb.y, bb.z, bb.w};
#pragma unroll
            for (int u = 0; u < 2; ++u)
#pragma unroll
                for (int v = 0; v < 4; ++v)
                    acc[u][v] = fmaf(av[u], bv[v], acc[u][v]);
        }
    }
    const float rni0 = rsqrtf(nsum[i0 + 2 * ty + 0]);
    const float rni1 = rsqrtf(nsum[i0 + 2 * ty + 1]);
    float rp0 = 0.f, rp1 = 0.f;
#pragma unroll
    for (int v = 0; v < 4; ++v) {
        const int j = j0 + 4 * tx + v;
        const bool jv = (j < C_CLS);
        const float rnj = rsqrtf(nsum[j]);
        const float d0 = acc[0][v] * rni0 * rnj;
        const float d1 = acc[1][v] * rni1 * rnj;
        const float w0 = (jv && d0 > 0.5f) ? __expf(10.f * d0) : 0.f;
        const float w1 = (jv && d1 > 0.5f) ? __expf(10.f * d1) : 0.f;
        rp0 += w0; rp1 += w1;
        *(float2*)(WT + (size_t)j * CP + i0 + 2 * ty) = make_float2(w0, w1);
    }
    sm.s.rp[2 * ty + 0][tx] = rp0;
    sm.s.rp[2 * ty + 1][tx] = rp1;
    __syncthreads();
    if (t < 64) {
        float s = 0.f;
#pragma unroll 16
        for (int k = 0; k < 16; ++k) s += sm.s.rp[t][k];
        const int i = i0 + t;
        if (i < C_CLS) atomicAdd(&rsum[i], s);
    }
}

// ---------------------------------------------------------------------------
// mm1 (split-K x2): Q[kz] = W @ V partial GEMM from WT. 256 blocks (8c x 16i
// x 2kz), 64x64 tile, 2i x 4c per thread.
// ---------------------------------------------------------------------------
__device__ __forceinline__ void mm_dev(BSm& sm, int b, int t,
    const float* __restrict__ WT, const float* __restrict__ V,
    float* __restrict__ Q)
{
    const int c0 = (b & 7) * 64;
    const int i0 = ((b >> 3) & 15) * 64;
    const int kz = b >> 7;
    const int tx = t & 15, ty = t >> 4;
    float acc[2][4] = {};
    for (int ch = 0; ch < 8; ++ch) {
        const int kb = kz * 512 + ch * 64;
        __syncthreads();
        for (int l = t; l < 1024; l += 512) {
            const int kk = l >> 4, f = l & 15;
            *(float4*)&sm.m.Wt[kk][4 * f] =
                *(const float4*)(WT + (size_t)(kb + kk) * CP + i0 + 4 * f);
            const int jc = min(kb + kk, C_CLS - 1);
            *(float4*)&sm.m.Vt[kk][4 * f] =
                *(const float4*)(V + (size_t)jc * DIM + c0 + 4 * f);
        }
        __syncthreads();
#pragma unroll 8
        for (int kk = 0; kk < 64; ++kk) {
            const float2 w = *(const float2*)&sm.m.Wt[kk][2 * ty];
            const float4 v = *(const float4*)&sm.m.Vt[kk][4 * tx];
            const float wv[2] = {w.x, w.y};
            const float vv[4] = {v.x, v.y, v.z, v.w};
#pragma unroll
            for (int u = 0; u < 2; ++u)
#pragma unroll
                for (int cv = 0; cv < 4; ++cv)
                    acc[u][cv] = fmaf(wv[u], vv[cv], acc[u][cv]);
        }
    }
    float* dst = Q + (size_t)kz * CP * DIM;
#pragma unroll
    for (int u = 0; u < 2; ++u) {
        const int i = i0 + 2 * ty + u;
        float4 o = {acc[u][0], acc[u][1], acc[u][2], acc[u][3]};
        *(float4*)(dst + (size_t)i * DIM + c0 + 4 * tx) = o;
    }
}

// ---------------------------------------------------------------------------
// mm_out (full-K, 256 blocks): out[i] = (W @ V)[i] / rsum[i], V via vidx.
// grid (8c x 32i), tile 32i x 64c, K=1024 in 16 chunks, 1i x 4c per thread.
// ---------------------------------------------------------------------------
__device__ __forceinline__ void mm_out_dev(BSm& sm, int b, int t,
    const float* __restrict__ WT, const float* __restrict__ V,
    const int* __restrict__ vidx, const float* __restrict__ rsum,
    float* __restrict__ Out)
{
    const int c0 = (b & 7) * 64;
    const int i0 = (b >> 3) * 32;
    const int tx = t & 15, ty = t >> 4;   // ty 0..31 = i
    float acc[4] = {};
    for (int ch = 0; ch < 16; ++ch) {
        const int kb = ch * 64;
        __syncthreads();
        // W-tile (64 k x 32 i): one float4 per thread
        {
            const int kk = t >> 3, f = t & 7;
            *(float4*)&sm.m2.Wt[kk][4 * f] =
                *(const float4*)(WT + (size_t)(kb + kk) * CP + i0 + 4 * f);
        }
        // V-tile (64 k x 64 c): two float4 per thread
        for (int l = t; l < 1024; l += 512) {
            const int kk = l >> 4, f = l & 15;
            const int jc = min(kb + kk, C_CLS - 1);
            const int vr = vidx[jc];
            *(float4*)&sm.m2.Vt[kk][4 * f] =
                *(const float4*)(V + (size_t)vr * DIM + c0 + 4 * f);
        }
        __syncthreads();
#pragma unroll 8
        for (int kk = 0; kk < 64; ++kk) {
            const float  w = sm.m2.Wt[kk][ty];
            const float4 v = *(const float4*)&sm.m2.Vt[kk][4 * tx];
            acc[0] = fmaf(w, v.x, acc[0]);
            acc[1] = fmaf(w, v.y, acc[1]);
            acc[2] = fmaf(w, v.z, acc[2]);
            acc[3] = fmaf(w, v.w, acc[3]);
        }
    }
    const int i = i0 + ty;
    if (i < C_CLS) {
        const float s = 1.0f / rsum[i];
        float4 o = {acc[0] * s, acc[1] * s, acc[2] * s, acc[3] * s};
        *(float4*)(Out + (size_t)i * DIM + c0 + 4 * tx) = o;
    }
}

// ---------------------------------------------------------------------------
// Kernels
// ---------------------------------------------------------------------------
__global__ __launch_bounds__(512) void k_proj_fill(
    const float* __restrict__ A0, const float* __restrict__ Wm,
    float* __restrict__ PT, float* __restrict__ nsum,
    const int* __restrict__ labels, int* __restrict__ cnt,
    int* __restrict__ perm)
{
    __shared__ BSm sm;
    const int b = blockIdx.x, t = threadIdx.x;
    if (b < 256) {
        proj_dev(sm, b, t, A0, nullptr, nullptr, Wm, PT, nsum);
    } else {
        const int i = (b - 256) * 512 + t;
        if (i < N_IMG) {
            const int c = labels[i];
            const int p = atomicAdd(&cnt[c], 1);
            if (p < CAP) perm[c * CAP + p] = i;
        }
    }
}

__global__ __launch_bounds__(512) void k_score_gather(
    const float* __restrict__ PT, const float* __restrict__ nsum,
    float* __restrict__ WT, float* __restrict__ rsum,
    const float* __restrict__ image_feats, const int* __restrict__ cnt,
    const int* __restrict__ perm, float* __restrict__ protos, int cbase)
{
    __shared__ BSm sm;
    const int b = blockIdx.x, t = threadIdx.x;
    if (b < 256) score_dev(sm, b, t, PT, nsum, WT, rsum);
    else         gather_dev(sm, cbase + (b - 256), t, image_feats, cnt, perm, protos);
}

__global__ __launch_bounds__(512) void k_mm_gather(
    const float* __restrict__ WT, const float* __restrict__ V,
    float* __restrict__ Q,
    const float* __restrict__ image_feats, const int* __restrict__ cnt,
    const int* __restrict__ perm, float* __restrict__ protos, int cbase)
{
    __shared__ BSm sm;
    const int b = blockIdx.x, t = threadIdx.x;
    if (b < 256) mm_dev(sm, b, t, WT, V, Q);
    else         gather_dev(sm, cbase + (b - 256), t, image_feats, cnt, perm, protos);
}

__global__ __launch_bounds__(512) void k_proj_gather(
    const float* __restrict__ Qp, const float* __restrict__ rsum_in,
    const float* __restrict__ Wm, float* __restrict__ PT,
    float* __restrict__ nsum,
    const float* __restrict__ image_feats, const int* __restrict__ cnt,
    const int* __restrict__ perm, float* __restrict__ protos, int cbase)
{
    __shared__ BSm sm;
    const int b = blockIdx.x, t = threadIdx.x;
    if (b < 256) proj_dev(sm, b, t, nullptr, Qp, rsum_in, Wm, PT, nsum);
    else         gather_dev(sm, cbase + (b - 256), t, image_feats, cnt, perm, protos);
}

__global__ __launch_bounds__(512) void k_mm_out(
    const float* __restrict__ WT, const float* __restrict__ V,
    const int* __restrict__ vidx, const float* __restrict__ rsum,
    float* __restrict__ Out)
{
    __shared__ BSm sm;
    mm_out_dev(sm, blockIdx.x, threadIdx.x, WT, V, vidx, rsum, Out);
}

// ---------------------------------------------------------------------------
extern "C" void kernel_launch(void* const* d_in, const int* in_sizes, int n_in,
                              void* d_out, int out_size, void* d_ws, size_t ws_size,
                              hipStream_t stream) {
    const float* image_feats = (const float*)d_in[0];  // [100000, 512]
    const float* attributes  = (const float*)d_in[1];  // [1000, 512]
    const float* att_g       = (const float*)d_in[2];  // [512, 256]
    const float* att_h       = (const float*)d_in[3];  // [512, 256]
    const int*   labels      = (const int*)d_in[4];    // [100000]
    const int*   tpl         = (const int*)d_in[5];    // [1000]
    float* out = (float*)d_out;                        // [1000, 512]

    float* ws     = (float*)d_ws;
    float* protos = ws;                       // 512000
    float* PT     = protos + 512000;          // 262144  [256][1024]
    float* WT     = PT + 262144;              // 1048576 [1024][1024]
    float* Qpart  = WT + 1048576;             // 1048576 [2][1024][512]
    int*   cnt    = (int*)(Qpart + 1048576);  // 1024  (zero-block start)
    float* rsum1  = (float*)(cnt + 1024);     // 1024
    float* rsum2  = rsum1 + 1024;             // 1024
    float* nsum1  = rsum2 + 1024;             // 1024
    float* nsum2  = nsum1 + 1024;             // 1024
    int*   perm   = (int*)(nsum2 + 1024);     // 512000

    hipMemsetAsync(cnt, 0, 5 * 1024 * sizeof(int), stream);

    // K1: proj1 (attributes @ att_h -> PT, nsum1) ∥ fill
    k_proj_fill<<<256 + 196, 512, 0, stream>>>(
        attributes, att_h, PT, nsum1, labels, cnt, perm);
    // K2: score1 ∥ gather [0,250)
    k_score_gather<<<256 + 250, 512, 0, stream>>>(
        PT, nsum1, WT, rsum1, image_feats, cnt, perm, protos, 0);
    // K3: mm1 (split-K) ∥ gather [250,500)
    k_mm_gather<<<256 + 250, 512, 0, stream>>>(
        WT, attributes, Qpart, image_feats, cnt, perm, protos, 250);
    // K4: proj2 (combine(Qpart)/rsum1 @ att_g -> PT, nsum2) ∥ gather [500,750)
    k_proj_gather<<<256 + 250, 512, 0, stream>>>(
        Qpart, rsum1, att_g, PT, nsum2, image_feats, cnt, perm, protos, 500);
    // K5: score2 ∥ gather [750,1000)
    k_score_gather<<<256 + 250, 512, 0, stream>>>(
        PT, nsum2, WT, rsum2, image_feats, cnt, perm, protos, 750);
    // K6: mm_out full-K, fused 1/rsum2 scale, writes out directly
    k_mm_out<<<256, 512, 0, stream>>>(WT, protos, tpl, rsum2, out);
}